// Round 7
// baseline (3203.863 us; speedup 1.0000x reference)
//
#include <hip/hip_runtime.h>
#include <hip/hip_bf16.h>

// MEASUREMENT ROUND 2: race three GEMM structures with in-kernel rep loops so
// each shows up in rocprof top-5 with full counters (fills are ~330us).
//   A (x96) : R2 structure — 2-buffer LDS, __syncthreads-drain per K-step.
//   B (x96) : R6 structure — 4-buffer LDS, lookahead-3, counted vmcnt.
//   C (x128): NEW — zero-LDS, zero-barrier GEMM reading frag-major A2/B2
//             (1KB fully-coalesced global loads straight into MFMA operands,
//             3-deep register prefetch rotation).
// Real output: R6 GEMM (known correct) runs LAST, writes d_out.
//
// out = value @ Wv + bv + key ;  M=2048, N=1024, K=1024

#define M_DIM 2048
#define N_DIM 1024
#define K_DIM 1024

#define REPS_A 96
#define REPS_B 96
#define REPS_C 128

typedef __attribute__((ext_vector_type(8))) short short8;
typedef __attribute__((ext_vector_type(4))) float f32x4;

__device__ inline unsigned rne_bf16(float f) {
    unsigned u = __builtin_bit_cast(unsigned, f);
    return (u + 0x7FFFu + ((u >> 16) & 1u)) >> 16;
}
__device__ inline unsigned pack2(float lo, float hi) {
    return rne_bf16(lo) | (rne_bf16(hi) << 16);
}
__device__ inline void gl_lds16(const short* g, short* l) {
    __builtin_amdgcn_global_load_lds((const __attribute__((address_space(1))) void*)g,
                                     (__attribute__((address_space(3))) void*)l,
                                     16, 0, 0);
}

// ---------------- K1: convert + transpose; emits BOTH layouts ----------------
// Tiled+swizzled (Vb, WvTb): tile (t,kt) = 4096 shorts; elem (r,kk) at
//   r*64 + ((c ^ (r&7))<<3) + (kk&7), c = kk>>3.
// Frag-major (A2, B2): per (t,kt) 4096 shorts ordered [ks][rg][lane*8]:
//   lane l holds rows rg*16+(l&15), k = ks*32 + (l>>4)*8 .. +8.
__global__ __launch_bounds__(256)
void convert_kernel(const float* __restrict__ value, const float* __restrict__ Wv,
                    short* __restrict__ Vb, short* __restrict__ WvTb,
                    short* __restrict__ A2, short* __restrict__ B2) {
    __shared__ unsigned tr[64 * 36];
    const int b = blockIdx.x, tid = threadIdx.x;
    if (b < 1024) {
        int g = b * 256 + tid;
        int row = g >> 7, ch = g & 127;
        int kt = ch >> 3, c = ch & 7;
        int tm = row >> 6, r = row & 63;
        const float* p = value + (size_t)row * K_DIM + ch * 8;
        f32x4 a0 = *(const f32x4*)p;
        f32x4 a1 = *(const f32x4*)(p + 4);
        union { short8 s; unsigned u[4]; } o;
        o.u[0] = pack2(a0[0], a0[1]);
        o.u[1] = pack2(a0[2], a0[3]);
        o.u[2] = pack2(a1[0], a1[1]);
        o.u[3] = pack2(a1[2], a1[3]);
        *(short8*)&Vb[(size_t)(tm * 16 + kt) * 4096 + r * 64 + ((c ^ (r & 7)) << 3)] = o.s;
        // frag-major copy: ks = c>>2, chunk-in-slab cc = c&3 -> lane = cc*16 + (r&15)
        {
            int ks = c >> 2, cc = c & 3, rg = r >> 4, l = cc * 16 + (r & 15);
            *(short8*)&A2[(size_t)(tm * 16 + kt) * 4096 + (ks * 4 + rg) * 512 + l * 8] = o.s;
        }
    } else {
        int b2 = b - 1024;
        int tn = b2 & 15, kt = b2 >> 4;
        #pragma unroll
        for (int s = 0; s < 2; ++s) {
            int kp = (tid >> 4) + s * 16;
            int n4 = (tid & 15) * 4;
            const float* bp = Wv + (size_t)(kt * 64 + 2 * kp) * N_DIM + tn * 64 + n4;
            f32x4 b0 = *(const f32x4*)bp;
            f32x4 b1 = *(const f32x4*)(bp + N_DIM);
            #pragma unroll
            for (int m = 0; m < 4; ++m)
                tr[(n4 + m) * 36 + kp] = pack2(b0[m], b1[m]);
        }
        __syncthreads();
        int n = tid >> 2;
        #pragma unroll
        for (int h = 0; h < 2; ++h) {
            int c = (tid & 3) + 4 * h;
            union { short8 s; unsigned u[4]; } o;
            #pragma unroll
            for (int p = 0; p < 4; ++p)
                o.u[p] = tr[n * 36 + c * 4 + p];
            *(short8*)&WvTb[(size_t)(tn * 16 + kt) * 4096 + n * 64 + ((c ^ (n & 7)) << 3)] = o.s;
            // frag-major: ks = h, cc = tid&3, lane = cc*16 + (n&15), cg = n>>4
            {
                int cc = tid & 3, cg = n >> 4, l = cc * 16 + (n & 15);
                *(short8*)&B2[(size_t)(tn * 16 + kt) * 4096 + (h * 4 + cg) * 512 + l * 8] = o.s;
            }
        }
    }
}

// ================= variant A: R2 structure (rep) =================
__global__ __launch_bounds__(256)
void gemmA_rep(const short* __restrict__ Vb, const short* __restrict__ WvTb,
               const float* __restrict__ key, const float* __restrict__ bv,
               float* __restrict__ out) {
    __shared__ __align__(16) short As[2][4096];
    __shared__ __align__(16) short Bs[2][4096];
    const int tid = threadIdx.x, bid = blockIdx.x;
    const int swz = ((bid & 7) << 6) | (bid >> 3);
    const int bm = swz >> 4, bn = swz & 15;
    const int lane = tid & 63, wid = tid >> 6, wr = wid >> 1, wc = wid & 1;
    const short* Abase = Vb + (size_t)bm * 16 * 4096;
    const short* Bbase = WvTb + (size_t)bn * 16 * 4096;
    const int row0 = bm * 64, col0 = bn * 64;
    const int colA = col0 + wc * 32 + (lane & 15);
    const int rbaseA = row0 + wr * 32 + ((lane >> 4) * 4);

    #pragma unroll 1
    for (int rep = 0; rep < REPS_A; ++rep) {
        asm volatile("" ::: "memory");
        float keyr[2][2][4], bvr[2];
        #pragma unroll
        for (int fn = 0; fn < 2; ++fn) bvr[fn] = bv[colA + fn * 16];
        #pragma unroll
        for (int fm = 0; fm < 2; ++fm)
            #pragma unroll
            for (int fn = 0; fn < 2; ++fn)
                #pragma unroll
                for (int i = 0; i < 4; ++i)
                    keyr[fm][fn][i] = key[(size_t)(rbaseA + fm * 16 + i) * N_DIM + colA + fn * 16];
        f32x4 acc[2][2] = {};
        auto stage = [&](int buf, int kt) {
            const short* ga = Abase + (size_t)kt * 4096 + tid * 8;
            const short* gb = Bbase + (size_t)kt * 4096 + tid * 8;
            gl_lds16(ga, &As[buf][tid * 8]);
            gl_lds16(ga + 2048, &As[buf][2048 + tid * 8]);
            gl_lds16(gb, &Bs[buf][tid * 8]);
            gl_lds16(gb + 2048, &Bs[buf][2048 + tid * 8]);
        };
        auto compute = [&](int buf) {
            #pragma unroll
            for (int ks = 0; ks < 2; ++ks) {
                short8 afr[2], bfr[2];
                const int g = ks * 4 + (lane >> 4);
                #pragma unroll
                for (int fm = 0; fm < 2; ++fm) {
                    int r = wr * 32 + fm * 16 + (lane & 15);
                    afr[fm] = *(const short8*)&As[buf][r * 64 + ((g ^ (r & 7)) << 3)];
                }
                #pragma unroll
                for (int fn = 0; fn < 2; ++fn) {
                    int n = wc * 32 + fn * 16 + (lane & 15);
                    bfr[fn] = *(const short8*)&Bs[buf][n * 64 + ((g ^ (n & 7)) << 3)];
                }
                #pragma unroll
                for (int fm = 0; fm < 2; ++fm)
                    #pragma unroll
                    for (int fn = 0; fn < 2; ++fn)
                        acc[fm][fn] = __builtin_amdgcn_mfma_f32_16x16x32_bf16(
                            afr[fm], bfr[fn], acc[fm][fn], 0, 0, 0);
            }
        };
        stage(0, 0);
        __syncthreads();
        #pragma unroll 1
        for (int kt = 0; kt < 16; ++kt) {
            if (kt < 15) stage((kt + 1) & 1, kt + 1);
            compute(kt & 1);
            __syncthreads();
        }
        #pragma unroll
        for (int fm = 0; fm < 2; ++fm)
            #pragma unroll
            for (int fn = 0; fn < 2; ++fn) {
                int col = colA + fn * 16;
                #pragma unroll
                for (int i = 0; i < 4; ++i) {
                    int r = rbaseA + fm * 16 + i;
                    out[(size_t)r * N_DIM + col] = acc[fm][fn][i] + bvr[fn] + keyr[fm][fn][i];
                }
            }
        __syncthreads();
    }
}

// ================= variant B: R6 structure (REPS>0: rep->scratch; 0: real) ==
template <int REPS>
__global__ __launch_bounds__(256)
void gemmB_k(const short* __restrict__ Vb, const short* __restrict__ WvTb,
             const float* __restrict__ key, const float* __restrict__ bv,
             float* __restrict__ out) {
    __shared__ __align__(16) short As[4][4096];
    __shared__ __align__(16) short Bs[4][4096];
    const int tid = threadIdx.x, bid = blockIdx.x;
    const int swz = ((bid & 7) << 6) | (bid >> 3);
    const int bm = swz >> 4, bn = swz & 15;
    const int lane = tid & 63, wid = tid >> 6, wr = wid >> 1, wc = wid & 1;
    const short* Abase = Vb + (size_t)bm * 16 * 4096;
    const short* Bbase = WvTb + (size_t)bn * 16 * 4096;
    const int row0 = bm * 64, col0 = bn * 64;
    const int colA = col0 + wc * 32 + (lane & 15);
    const int rbaseA = row0 + wr * 32 + ((lane >> 4) * 4);

    #pragma unroll 1
    for (int rep = 0; rep < (REPS ? REPS : 1); ++rep) {
        asm volatile("" ::: "memory");
        float keyr[2][2][4], bvr[2];
        #pragma unroll
        for (int fn = 0; fn < 2; ++fn) bvr[fn] = bv[colA + fn * 16];
        #pragma unroll
        for (int fm = 0; fm < 2; ++fm)
            #pragma unroll
            for (int fn = 0; fn < 2; ++fn)
                #pragma unroll
                for (int i = 0; i < 4; ++i)
                    keyr[fm][fn][i] = key[(size_t)(rbaseA + fm * 16 + i) * N_DIM + colA + fn * 16];
        f32x4 acc[2][2] = {};
        auto stage = [&](int buf, int kt) {
            const short* ga = Abase + (size_t)kt * 4096 + tid * 8;
            const short* gb = Bbase + (size_t)kt * 4096 + tid * 8;
            gl_lds16(ga, &As[buf][tid * 8]);
            gl_lds16(ga + 2048, &As[buf][2048 + tid * 8]);
            gl_lds16(gb, &Bs[buf][tid * 8]);
            gl_lds16(gb + 2048, &Bs[buf][2048 + tid * 8]);
        };
        auto compute = [&](int buf) {
            #pragma unroll
            for (int ks = 0; ks < 2; ++ks) {
                short8 afr[2], bfr[2];
                const int g = ks * 4 + (lane >> 4);
                #pragma unroll
                for (int fm = 0; fm < 2; ++fm) {
                    int r = wr * 32 + fm * 16 + (lane & 15);
                    afr[fm] = *(const short8*)&As[buf][r * 64 + ((g ^ (r & 7)) << 3)];
                }
                #pragma unroll
                for (int fn = 0; fn < 2; ++fn) {
                    int n = wc * 32 + fn * 16 + (lane & 15);
                    bfr[fn] = *(const short8*)&Bs[buf][n * 64 + ((g ^ (n & 7)) << 3)];
                }
                #pragma unroll
                for (int fm = 0; fm < 2; ++fm)
                    #pragma unroll
                    for (int fn = 0; fn < 2; ++fn)
                        acc[fm][fn] = __builtin_amdgcn_mfma_f32_16x16x32_bf16(
                            afr[fm], bfr[fn], acc[fm][fn], 0, 0, 0);
            }
        };
        stage(0, 0);
        stage(1, 1);
        stage(2, 2);
        #pragma unroll
        for (int kt = 0; kt < 16; ++kt) {
            if (kt <= 13)      asm volatile("s_waitcnt vmcnt(8)" ::: "memory");
            else if (kt == 14) asm volatile("s_waitcnt vmcnt(4)" ::: "memory");
            else               asm volatile("s_waitcnt vmcnt(0)" ::: "memory");
            __builtin_amdgcn_s_barrier();
            if (kt + 3 < 16) stage((kt + 3) & 3, kt + 3);
            compute(kt & 3);
        }
        #pragma unroll
        for (int fm = 0; fm < 2; ++fm)
            #pragma unroll
            for (int fn = 0; fn < 2; ++fn) {
                int col = colA + fn * 16;
                #pragma unroll
                for (int i = 0; i < 4; ++i) {
                    int r = rbaseA + fm * 16 + i;
                    out[(size_t)r * N_DIM + col] = acc[fm][fn][i] + bvr[fn] + keyr[fm][fn][i];
                }
            }
        if (REPS) {  // drain stores so next rep's counted vmcnt stays exact
            asm volatile("s_waitcnt vmcnt(0)" ::: "memory");
            __syncthreads();
        }
    }
}

// ================= variant C: zero-LDS zero-barrier frag-direct (rep) =======
__global__ __launch_bounds__(256)
void gemmC_rep(const short* __restrict__ A2, const short* __restrict__ B2,
               const float* __restrict__ key, const float* __restrict__ bv,
               float* __restrict__ out) {
    const int tid = threadIdx.x, bid = blockIdx.x;
    const int swz = ((bid & 7) << 6) | (bid >> 3);
    const int bm = swz >> 4, bn = swz & 15;
    const int lane = tid & 63, wid = tid >> 6, wr = wid >> 1, wc = wid & 1;
    const short* Ab = A2 + (size_t)bm * 16 * 4096 + lane * 8;
    const short* Bb = B2 + (size_t)bn * 16 * 4096 + lane * 8;
    const int row0 = bm * 64, col0 = bn * 64;
    const int colA = col0 + wc * 32 + (lane & 15);
    const int rbaseA = row0 + wr * 32 + ((lane >> 4) * 4);

    #pragma unroll 1
    for (int rep = 0; rep < REPS_C; ++rep) {
        asm volatile("" ::: "memory");
        float keyr[2][2][4], bvr[2];
        #pragma unroll
        for (int fn = 0; fn < 2; ++fn) bvr[fn] = bv[colA + fn * 16];
        #pragma unroll
        for (int fm = 0; fm < 2; ++fm)
            #pragma unroll
            for (int fn = 0; fn < 2; ++fn)
                #pragma unroll
                for (int i = 0; i < 4; ++i)
                    keyr[fm][fn][i] = key[(size_t)(rbaseA + fm * 16 + i) * N_DIM + colA + fn * 16];
        f32x4 acc[2][2] = {};
        short8 fa[3][4], fb[3][4];   // [slot][fm*2+ks] — all statically indexed
        auto issue = [&](int j, int kt) {
            #pragma unroll
            for (int ks = 0; ks < 2; ++ks)
                #pragma unroll
                for (int f = 0; f < 2; ++f) {
                    fa[j][f * 2 + ks] = *(const short8*)(Ab + (size_t)kt * 4096 + (ks * 4 + wr * 2 + f) * 512);
                    fb[j][f * 2 + ks] = *(const short8*)(Bb + (size_t)kt * 4096 + (ks * 4 + wc * 2 + f) * 512);
                }
        };
        issue(0, 0);
        issue(1, 1);
        #pragma unroll
        for (int kt = 0; kt < 16; ++kt) {
            if (kt + 2 < 16) issue((kt + 2) % 3, kt + 2);
            const int j = kt % 3;
            #pragma unroll
            for (int ks = 0; ks < 2; ++ks)
                #pragma unroll
                for (int fm = 0; fm < 2; ++fm)
                    #pragma unroll
                    for (int fn = 0; fn < 2; ++fn)
                        acc[fm][fn] = __builtin_amdgcn_mfma_f32_16x16x32_bf16(
                            fa[j][fm * 2 + ks], fb[j][fn * 2 + ks], acc[fm][fn], 0, 0, 0);
        }
        #pragma unroll
        for (int fm = 0; fm < 2; ++fm)
            #pragma unroll
            for (int fn = 0; fn < 2; ++fn) {
                int col = colA + fn * 16;
                #pragma unroll
                for (int i = 0; i < 4; ++i) {
                    int r = rbaseA + fm * 16 + i;
                    out[(size_t)r * N_DIM + col] = acc[fm][fn][i] + bvr[fn] + keyr[fm][fn][i];
                }
            }
    }
}

extern "C" void kernel_launch(void* const* d_in, const int* in_sizes, int n_in,
                              void* d_out, int out_size, void* d_ws, size_t ws_size,
                              hipStream_t stream) {
    // setup_inputs order: 0 query, 1 key, 2 value, 3 Wq, 4 bq, 5 Wk, 6 bk, 7 Wv, 8 bv, 9 U
    const float* key   = (const float*)d_in[1];
    const float* value = (const float*)d_in[2];
    const float* Wv    = (const float*)d_in[7];
    const float* bv    = (const float*)d_in[8];
    float* out = (float*)d_out;

    char* ws = (char*)d_ws;
    short* Vb    = (short*)(ws + 0);                   // 4 MB
    short* WvTb  = (short*)(ws + (4 << 20));           // 2 MB
    short* A2    = (short*)(ws + (6 << 20));           // 4 MB (frag-major)
    short* B2    = (short*)(ws + (10 << 20));          // 2 MB (frag-major)
    float* scrA  = (float*)(ws + (16 << 20));          // 8 MB scratch outs
    float* scrB  = (float*)(ws + (24 << 20));
    float* scrC  = (float*)(ws + (32 << 20));

    convert_kernel<<<1024 + 256, 256, 0, stream>>>(value, Wv, Vb, WvTb, A2, B2);
    gemmA_rep<<<512, 256, 0, stream>>>(Vb, WvTb, key, bv, scrA);
    gemmB_k<REPS_B><<<512, 256, 0, stream>>>(Vb, WvTb, key, bv, scrB);
    gemmC_rep<<<512, 256, 0, stream>>>(A2, B2, key, bv, scrC);
    gemmB_k<0><<<512, 256, 0, stream>>>(Vb, WvTb, key, bv, out);   // real output
}

// Round 8
// 2952.375 us; speedup vs baseline: 1.0852x; 1.0852x over previous
//
#include <hip/hip_runtime.h>
#include <hip/hip_bf16.h>

// MEASUREMENT ROUND 3: separate write-drain vs L2-read-BW hypotheses.
//   E1 (x192): reg-direct GEMM, full K, acc carried across reps, ONE store pass
//              at the end  -> pure load+MFMA probe (no per-rep stores).
//   E2 (x192): reg-direct GEMM, K=128 only, full scattered store pass EVERY rep
//              -> pure store-drain probe.
//   F  (real): R6 4-buffer pipelined LDS GEMM + NEW epilogue: acc -> LDS
//              transpose -> 256B-contiguous f32x4 stores (and f32x4 key reads).
// out = value @ Wv + bv + key ;  M=2048, N=1024, K=1024

#define M_DIM 2048
#define N_DIM 1024
#define K_DIM 1024

#define REPS_E1 192
#define REPS_E2 192

typedef __attribute__((ext_vector_type(8))) short short8;
typedef __attribute__((ext_vector_type(4))) float f32x4;

__device__ inline unsigned rne_bf16(float f) {
    unsigned u = __builtin_bit_cast(unsigned, f);
    return (u + 0x7FFFu + ((u >> 16) & 1u)) >> 16;
}
__device__ inline unsigned pack2(float lo, float hi) {
    return rne_bf16(lo) | (rne_bf16(hi) << 16);
}
__device__ inline void gl_lds16(const short* g, short* l) {
    __builtin_amdgcn_global_load_lds((const __attribute__((address_space(1))) void*)g,
                                     (__attribute__((address_space(3))) void*)l,
                                     16, 0, 0);
}

// ---------------- K1: convert + transpose; emits both layouts ----------------
__global__ __launch_bounds__(256)
void convert_kernel(const float* __restrict__ value, const float* __restrict__ Wv,
                    short* __restrict__ Vb, short* __restrict__ WvTb,
                    short* __restrict__ A2, short* __restrict__ B2) {
    __shared__ unsigned tr[64 * 36];
    const int b = blockIdx.x, tid = threadIdx.x;
    if (b < 1024) {
        int g = b * 256 + tid;
        int row = g >> 7, ch = g & 127;
        int kt = ch >> 3, c = ch & 7;
        int tm = row >> 6, r = row & 63;
        const float* p = value + (size_t)row * K_DIM + ch * 8;
        f32x4 a0 = *(const f32x4*)p;
        f32x4 a1 = *(const f32x4*)(p + 4);
        union { short8 s; unsigned u[4]; } o;
        o.u[0] = pack2(a0[0], a0[1]);
        o.u[1] = pack2(a0[2], a0[3]);
        o.u[2] = pack2(a1[0], a1[1]);
        o.u[3] = pack2(a1[2], a1[3]);
        *(short8*)&Vb[(size_t)(tm * 16 + kt) * 4096 + r * 64 + ((c ^ (r & 7)) << 3)] = o.s;
        int ks = c >> 2, cc = c & 3, rg = r >> 4, l = cc * 16 + (r & 15);
        *(short8*)&A2[(size_t)(tm * 16 + kt) * 4096 + (ks * 4 + rg) * 512 + l * 8] = o.s;
    } else {
        int b2 = b - 1024;
        int tn = b2 & 15, kt = b2 >> 4;
        #pragma unroll
        for (int s = 0; s < 2; ++s) {
            int kp = (tid >> 4) + s * 16;
            int n4 = (tid & 15) * 4;
            const float* bp = Wv + (size_t)(kt * 64 + 2 * kp) * N_DIM + tn * 64 + n4;
            f32x4 b0 = *(const f32x4*)bp;
            f32x4 b1 = *(const f32x4*)(bp + N_DIM);
            #pragma unroll
            for (int m = 0; m < 4; ++m)
                tr[(n4 + m) * 36 + kp] = pack2(b0[m], b1[m]);
        }
        __syncthreads();
        int n = tid >> 2;
        #pragma unroll
        for (int h = 0; h < 2; ++h) {
            int c = (tid & 3) + 4 * h;
            union { short8 s; unsigned u[4]; } o;
            #pragma unroll
            for (int p = 0; p < 4; ++p)
                o.u[p] = tr[n * 36 + c * 4 + p];
            *(short8*)&WvTb[(size_t)(tn * 16 + kt) * 4096 + n * 64 + ((c ^ (n & 7)) << 3)] = o.s;
            int cc = tid & 3, cg = n >> 4, l = cc * 16 + (n & 15);
            *(short8*)&B2[(size_t)(tn * 16 + kt) * 4096 + (h * 4 + cg) * 512 + l * 8] = o.s;
        }
    }
}

// ================= E1: load+MFMA probe (stores once at end) =================
__global__ __launch_bounds__(256)
void gemmE1(const short* __restrict__ A2, const short* __restrict__ B2,
            const float* __restrict__ key, const float* __restrict__ bv,
            float* __restrict__ out) {
    const int tid = threadIdx.x, bid = blockIdx.x;
    const int swz = ((bid & 7) << 6) | (bid >> 3);
    const int bm = swz >> 4, bn = swz & 15;
    const int lane = tid & 63, wid = tid >> 6, wr = wid >> 1, wc = wid & 1;
    const short* Ab = A2 + (size_t)bm * 16 * 4096 + lane * 8;
    const short* Bb = B2 + (size_t)bn * 16 * 4096 + lane * 8;
    const int row0 = bm * 64, col0 = bn * 64;
    const int colA = col0 + wc * 32 + (lane & 15);
    const int rbaseA = row0 + wr * 32 + ((lane >> 4) * 4);

    // key/bv loaded ONCE (scattered pattern, but amortized over all reps)
    float keyr[2][2][4], bvr[2];
    #pragma unroll
    for (int fn = 0; fn < 2; ++fn) bvr[fn] = bv[colA + fn * 16];
    #pragma unroll
    for (int fm = 0; fm < 2; ++fm)
        #pragma unroll
        for (int fn = 0; fn < 2; ++fn)
            #pragma unroll
            for (int i = 0; i < 4; ++i)
                keyr[fm][fn][i] = key[(size_t)(rbaseA + fm * 16 + i) * N_DIM + colA + fn * 16];

    f32x4 acc[2][2] = {};   // carried across reps -> no rep is dead code
    #pragma unroll 1
    for (int rep = 0; rep < REPS_E1; ++rep) {
        asm volatile("" ::: "memory");
        short8 fa[3][4], fb[3][4];
        auto issue = [&](int j, int kt) {
            #pragma unroll
            for (int ks = 0; ks < 2; ++ks)
                #pragma unroll
                for (int f = 0; f < 2; ++f) {
                    fa[j][f * 2 + ks] = *(const short8*)(Ab + (size_t)kt * 4096 + (ks * 4 + wr * 2 + f) * 512);
                    fb[j][f * 2 + ks] = *(const short8*)(Bb + (size_t)kt * 4096 + (ks * 4 + wc * 2 + f) * 512);
                }
        };
        issue(0, 0);
        issue(1, 1);
        #pragma unroll
        for (int kt = 0; kt < 16; ++kt) {
            if (kt + 2 < 16) issue((kt + 2) % 3, kt + 2);
            const int j = kt % 3;
            #pragma unroll
            for (int ks = 0; ks < 2; ++ks)
                #pragma unroll
                for (int fm = 0; fm < 2; ++fm)
                    #pragma unroll
                    for (int fn = 0; fn < 2; ++fn)
                        acc[fm][fn] = __builtin_amdgcn_mfma_f32_16x16x32_bf16(
                            fa[j][fm * 2 + ks], fb[j][fn * 2 + ks], acc[fm][fn], 0, 0, 0);
        }
    }
    // single store pass (consumes every rep's MFMA chain)
    #pragma unroll
    for (int fm = 0; fm < 2; ++fm)
        #pragma unroll
        for (int fn = 0; fn < 2; ++fn) {
            int col = colA + fn * 16;
            #pragma unroll
            for (int i = 0; i < 4; ++i) {
                int r = rbaseA + fm * 16 + i;
                out[(size_t)r * N_DIM + col] = acc[fm][fn][i] + bvr[fn] + keyr[fm][fn][i];
            }
        }
}

// ================= E2: store-drain probe (K=128, stores every rep) ==========
__global__ __launch_bounds__(256)
void gemmE2(const short* __restrict__ A2, const short* __restrict__ B2,
            const float* __restrict__ key, const float* __restrict__ bv,
            float* __restrict__ out) {
    const int tid = threadIdx.x, bid = blockIdx.x;
    const int swz = ((bid & 7) << 6) | (bid >> 3);
    const int bm = swz >> 4, bn = swz & 15;
    const int lane = tid & 63, wid = tid >> 6, wr = wid >> 1, wc = wid & 1;
    const short* Ab = A2 + (size_t)bm * 16 * 4096 + lane * 8;
    const short* Bb = B2 + (size_t)bn * 16 * 4096 + lane * 8;
    const int row0 = bm * 64, col0 = bn * 64;
    const int colA = col0 + wc * 32 + (lane & 15);
    const int rbaseA = row0 + wr * 32 + ((lane >> 4) * 4);

    float keyr[2][2][4], bvr[2];
    #pragma unroll
    for (int fn = 0; fn < 2; ++fn) bvr[fn] = bv[colA + fn * 16];
    #pragma unroll
    for (int fm = 0; fm < 2; ++fm)
        #pragma unroll
        for (int fn = 0; fn < 2; ++fn)
            #pragma unroll
            for (int i = 0; i < 4; ++i)
                keyr[fm][fn][i] = key[(size_t)(rbaseA + fm * 16 + i) * N_DIM + colA + fn * 16];

    f32x4 acc[2][2] = {};
    #pragma unroll 1
    for (int rep = 0; rep < REPS_E2; ++rep) {
        asm volatile("" ::: "memory");
        short8 fa[2][4], fb[2][4];
        auto issue = [&](int j, int kt) {
            #pragma unroll
            for (int ks = 0; ks < 2; ++ks)
                #pragma unroll
                for (int f = 0; f < 2; ++f) {
                    fa[j][f * 2 + ks] = *(const short8*)(Ab + (size_t)kt * 4096 + (ks * 4 + wr * 2 + f) * 512);
                    fb[j][f * 2 + ks] = *(const short8*)(Bb + (size_t)kt * 4096 + (ks * 4 + wc * 2 + f) * 512);
                }
        };
        issue(0, 0);
        issue(1, 1);
        #pragma unroll
        for (int j = 0; j < 2; ++j)
            #pragma unroll
            for (int ks = 0; ks < 2; ++ks)
                #pragma unroll
                for (int fm = 0; fm < 2; ++fm)
                    #pragma unroll
                    for (int fn = 0; fn < 2; ++fn)
                        acc[fm][fn] = __builtin_amdgcn_mfma_f32_16x16x32_bf16(
                            fa[j][fm * 2 + ks], fb[j][fn * 2 + ks], acc[fm][fn], 0, 0, 0);
        // full scattered store pass EVERY rep (the original epilogue pattern)
        #pragma unroll
        for (int fm = 0; fm < 2; ++fm)
            #pragma unroll
            for (int fn = 0; fn < 2; ++fn) {
                int col = colA + fn * 16;
                #pragma unroll
                for (int i = 0; i < 4; ++i) {
                    int r = rbaseA + fm * 16 + i;
                    out[(size_t)r * N_DIM + col] = acc[fm][fn][i] + bvr[fn] + keyr[fm][fn][i];
                }
            }
    }
}

// ================= F: real kernel — R6 pipeline + contiguous epilogue =======
__global__ __launch_bounds__(256)
void gemmF(const short* __restrict__ Vb, const short* __restrict__ WvTb,
           const float* __restrict__ key, const float* __restrict__ bv,
           float* __restrict__ out) {
    __shared__ __align__(16) short As[4][4096];
    __shared__ __align__(16) short Bs[4][4096];
    const int tid = threadIdx.x, bid = blockIdx.x;
    const int swz = ((bid & 7) << 6) | (bid >> 3);
    const int bm = swz >> 4, bn = swz & 15;
    const int lane = tid & 63, wid = tid >> 6, wr = wid >> 1, wc = wid & 1;
    const short* Abase = Vb + (size_t)bm * 16 * 4096;
    const short* Bbase = WvTb + (size_t)bn * 16 * 4096;
    const int row0 = bm * 64, col0 = bn * 64;

    f32x4 acc[2][2] = {};
    auto stage = [&](int buf, int kt) {
        const short* ga = Abase + (size_t)kt * 4096 + tid * 8;
        const short* gb = Bbase + (size_t)kt * 4096 + tid * 8;
        gl_lds16(ga, &As[buf][tid * 8]);
        gl_lds16(ga + 2048, &As[buf][2048 + tid * 8]);
        gl_lds16(gb, &Bs[buf][tid * 8]);
        gl_lds16(gb + 2048, &Bs[buf][2048 + tid * 8]);
    };
    auto compute = [&](int buf) {
        #pragma unroll
        for (int ks = 0; ks < 2; ++ks) {
            short8 afr[2], bfr[2];
            const int g = ks * 4 + (lane >> 4);
            #pragma unroll
            for (int fm = 0; fm < 2; ++fm) {
                int r = wr * 32 + fm * 16 + (lane & 15);
                afr[fm] = *(const short8*)&As[buf][r * 64 + ((g ^ (r & 7)) << 3)];
            }
            #pragma unroll
            for (int fn = 0; fn < 2; ++fn) {
                int n = wc * 32 + fn * 16 + (lane & 15);
                bfr[fn] = *(const short8*)&Bs[buf][n * 64 + ((g ^ (n & 7)) << 3)];
            }
            #pragma unroll
            for (int fm = 0; fm < 2; ++fm)
                #pragma unroll
                for (int fn = 0; fn < 2; ++fn)
                    acc[fm][fn] = __builtin_amdgcn_mfma_f32_16x16x32_bf16(
                        afr[fm], bfr[fn], acc[fm][fn], 0, 0, 0);
        }
    };

    stage(0, 0);
    stage(1, 1);
    stage(2, 2);
    #pragma unroll
    for (int kt = 0; kt < 16; ++kt) {
        if (kt <= 13)      asm volatile("s_waitcnt vmcnt(8)" ::: "memory");
        else if (kt == 14) asm volatile("s_waitcnt vmcnt(4)" ::: "memory");
        else               asm volatile("s_waitcnt vmcnt(0)" ::: "memory");
        __builtin_amdgcn_s_barrier();
        if (kt + 3 < 16) stage((kt + 3) & 3, kt + 3);
        compute(kt & 3);
    }

    // ---- NEW epilogue: acc -> LDS (64x68 f32) -> contiguous 256B row segments
    __syncthreads();                       // all waves done with As/Bs
    float* T = (float*)&As[0][0];          // 64*68*4 B = 17.4 KB, fits
    #pragma unroll
    for (int fm = 0; fm < 2; ++fm)
        #pragma unroll
        for (int fn = 0; fn < 2; ++fn) {
            int c = wc * 32 + fn * 16 + (lane & 15);
            #pragma unroll
            for (int i = 0; i < 4; ++i) {
                int r = wr * 32 + fm * 16 + (lane >> 4) * 4 + i;
                T[r * 68 + c] = acc[fm][fn][i];
            }
        }
    __syncthreads();
    #pragma unroll
    for (int it = 0; it < 4; ++it) {
        int r = it * 16 + (tid >> 4);      // 16 rows per iteration
        int q = tid & 15;                  // 16 quads cover 64 cols
        f32x4 vv = *(f32x4*)&T[r * 68 + q * 4];
        int grow = row0 + r, gcol = col0 + q * 4;
        f32x4 kv = *(const f32x4*)&key[(size_t)grow * N_DIM + gcol];
        f32x4 bb = *(const f32x4*)&bv[gcol];
        vv = vv + kv + bb;
        *(f32x4*)&out[(size_t)grow * N_DIM + gcol] = vv;
    }
}

extern "C" void kernel_launch(void* const* d_in, const int* in_sizes, int n_in,
                              void* d_out, int out_size, void* d_ws, size_t ws_size,
                              hipStream_t stream) {
    // setup_inputs order: 0 query, 1 key, 2 value, 3 Wq, 4 bq, 5 Wk, 6 bk, 7 Wv, 8 bv, 9 U
    const float* key   = (const float*)d_in[1];
    const float* value = (const float*)d_in[2];
    const float* Wv    = (const float*)d_in[7];
    const float* bv    = (const float*)d_in[8];
    float* out = (float*)d_out;

    char* ws = (char*)d_ws;
    short* Vb    = (short*)(ws + 0);           // 4 MB
    short* WvTb  = (short*)(ws + (4 << 20));   // 2 MB
    short* A2    = (short*)(ws + (6 << 20));   // 4 MB
    short* B2    = (short*)(ws + (10 << 20));  // 2 MB
    float* scrE1 = (float*)(ws + (16 << 20));  // 8 MB
    float* scrE2 = (float*)(ws + (24 << 20));  // 8 MB

    convert_kernel<<<1024 + 256, 256, 0, stream>>>(value, Wv, Vb, WvTb, A2, B2);
    gemmE1<<<512, 256, 0, stream>>>(A2, B2, key, bv, scrE1);
    gemmE2<<<512, 256, 0, stream>>>(A2, B2, key, bv, scrE2);
    gemmF<<<512, 256, 0, stream>>>(Vb, WvTb, key, bv, out);   // real output
}

// Round 9
// 26.532 us; speedup vs baseline: 120.7543x; 111.2757x over previous
//
#include <hip/hip_runtime.h>
#include <hip/hip_bf16.h>

// out = value @ Wv + bv + key   (softmax over [.,.,1,1] is identically 1 -> ctx == v)
// M=2048 (batch), N=1024 (d_model out), K=1024 (d_model in)
//
// R8 findings: all 64x64 variants are L2-READ-BW-bound (~134-256MB panel reads,
// 17-22 TB/s); stores are L2-absorbed and cheap. Fix: 128x64 tiles -> 96MB reads,
// still 256 blocks (full chip).
//
// K1 convert: value f32 -> Vb bf16 (64-row tiled+swizzled); Wv f32 -> WvTb bf16
//             [n][k] (tiled+swizzled).
// K2 GEMM:    128x64 tiles, BK=64, global_load_lds(16B), FOUR LDS buffers,
//             lookahead-3, counted vmcnt(12/6/0), ONE s_barrier per K-step,
//             4 waves = 2m x 2n, each wave 64x32 out (acc 4x2 frags),
//             key/bv reg-prefetch, XCD-swizzled blocks, fused epilogue.
//
// Tile layout (Vb, WvTb): tile (t, kt) = 4096 shorts at (t*16+kt)*4096;
// element (r, kk) at r*64 + ((c ^ (r&7))<<3) + (kk&7), c = kk>>3.

#define M_DIM 2048
#define N_DIM 1024
#define K_DIM 1024

typedef __attribute__((ext_vector_type(8))) short short8;
typedef __attribute__((ext_vector_type(4))) float f32x4;

__device__ inline unsigned rne_bf16(float f) {
    unsigned u = __builtin_bit_cast(unsigned, f);
    return (u + 0x7FFFu + ((u >> 16) & 1u)) >> 16;
}
__device__ inline unsigned pack2(float lo, float hi) {
    return rne_bf16(lo) | (rne_bf16(hi) << 16);
}
__device__ inline void gl_lds16(const short* g, short* l) {
    __builtin_amdgcn_global_load_lds((const __attribute__((address_space(1))) void*)g,
                                     (__attribute__((address_space(3))) void*)l,
                                     16, 0, 0);
}

// ---------------- K1: convert + transpose ----------------
__global__ __launch_bounds__(256)
void convert_kernel(const float* __restrict__ value, const float* __restrict__ Wv,
                    short* __restrict__ Vb, short* __restrict__ WvTb) {
    __shared__ unsigned tr[64 * 36];
    const int b = blockIdx.x, tid = threadIdx.x;
    if (b < 1024) {
        // value -> Vb : thread handles one 16B chunk (8 consecutive k) of one row
        int g = b * 256 + tid;
        int row = g >> 7, ch = g & 127;
        int kt = ch >> 3, c = ch & 7;
        int tm = row >> 6, r = row & 63;
        const float* p = value + (size_t)row * K_DIM + ch * 8;
        f32x4 a0 = *(const f32x4*)p;
        f32x4 a1 = *(const f32x4*)(p + 4);
        union { short8 s; unsigned u[4]; } o;
        o.u[0] = pack2(a0[0], a0[1]);
        o.u[1] = pack2(a0[2], a0[3]);
        o.u[2] = pack2(a1[0], a1[1]);
        o.u[3] = pack2(a1[2], a1[3]);
        *(short8*)&Vb[(size_t)(tm * 16 + kt) * 4096 + r * 64 + ((c ^ (r & 7)) << 3)] = o.s;
    } else {
        // Wv -> WvTb : one 64x64 tile per block, transpose via LDS (u32 = bf16 k-pair)
        int b2 = b - 1024;
        int tn = b2 & 15, kt = b2 >> 4;
        #pragma unroll
        for (int s = 0; s < 2; ++s) {
            int kp = (tid >> 4) + s * 16;           // k-pair index 0..31
            int n4 = (tid & 15) * 4;
            const float* bp = Wv + (size_t)(kt * 64 + 2 * kp) * N_DIM + tn * 64 + n4;
            f32x4 b0 = *(const f32x4*)bp;
            f32x4 b1 = *(const f32x4*)(bp + N_DIM);
            #pragma unroll
            for (int m = 0; m < 4; ++m)
                tr[(n4 + m) * 36 + kp] = pack2(b0[m], b1[m]);   // (k even, k odd)
        }
        __syncthreads();
        int n = tid >> 2;
        #pragma unroll
        for (int h = 0; h < 2; ++h) {
            int c = (tid & 3) + 4 * h;              // chunk 0..7
            union { short8 s; unsigned u[4]; } o;
            #pragma unroll
            for (int p = 0; p < 4; ++p)
                o.u[p] = tr[n * 36 + c * 4 + p];
            *(short8*)&WvTb[(size_t)(tn * 16 + kt) * 4096 + n * 64 + ((c ^ (n & 7)) << 3)] = o.s;
        }
    }
}

// ---------------- K2: 128x64-tile bf16 GEMM, 4-buffer lookahead-3 ----------------
__global__ __launch_bounds__(256)
void gemm_kernel(const short* __restrict__ Vb, const short* __restrict__ WvTb,
                 const float* __restrict__ key, const float* __restrict__ bv,
                 float* __restrict__ out) {
    __shared__ __align__(16) short As[4][8192];   // 64 KB: two 64-row tiles per buf
    __shared__ __align__(16) short Bs[4][4096];   // 32 KB

    const int tid = threadIdx.x;
    const int bid = blockIdx.x;
    // XCD swizzle: xcd = bid&7 owns 32 blocks = 2 bm2-bands x 16 bn.
    // Per-XCD L2 set: A 2x256KB + B 16x128KB = 2.5MB (fits 4MB).
    const int xcd = bid & 7, idx = bid >> 3;
    const int bm2 = xcd * 2 + (idx >> 4);   // 0..15  (128-row band)
    const int bn  = idx & 15;               // 0..15  (64-col band)
    const int lane = tid & 63;
    const int wid = tid >> 6;
    const int wr = wid >> 1;                // m-half (0..1): rows wr*64..+63
    const int wc = wid & 1;                 // n-half (0..1): cols wc*32..+31

    const short* Ab0 = Vb + (size_t)(bm2 * 2) * 16 * 4096;       // rows +0..63
    const short* Ab1 = Vb + (size_t)(bm2 * 2 + 1) * 16 * 4096;   // rows +64..127
    const short* Bb  = WvTb + (size_t)bn * 16 * 4096;
    const int row0 = bm2 * 128, col0 = bn * 64;

    // ---- key/bv reg-prefetch FIRST (oldest 34 VMEM ops; retire under K-loop)
    const int colA = col0 + wc * 32 + (lane & 15);
    const int rbaseA = row0 + wr * 64 + ((lane >> 4) * 4);
    float keyr[4][2][4];
    float bvr[2];
    #pragma unroll
    for (int fn = 0; fn < 2; ++fn) bvr[fn] = bv[colA + fn * 16];
    #pragma unroll
    for (int fm = 0; fm < 4; ++fm)
        #pragma unroll
        for (int fn = 0; fn < 2; ++fn)
            #pragma unroll
            for (int i = 0; i < 4; ++i)
                keyr[fm][fn][i] = key[(size_t)(rbaseA + fm * 16 + i) * N_DIM + colA + fn * 16];

    f32x4 acc[4][2] = {};

    auto stage = [&](int buf, int kt) {      // 6 x gl_lds16 per call
        const short* ga0 = Ab0 + (size_t)kt * 4096 + tid * 8;
        const short* ga1 = Ab1 + (size_t)kt * 4096 + tid * 8;
        const short* gb  = Bb  + (size_t)kt * 4096 + tid * 8;
        gl_lds16(ga0,        &As[buf][tid * 8]);
        gl_lds16(ga0 + 2048, &As[buf][2048 + tid * 8]);
        gl_lds16(ga1,        &As[buf][4096 + tid * 8]);
        gl_lds16(ga1 + 2048, &As[buf][6144 + tid * 8]);
        gl_lds16(gb,         &Bs[buf][tid * 8]);
        gl_lds16(gb + 2048,  &Bs[buf][2048 + tid * 8]);
    };

    auto compute = [&](int buf) {
        #pragma unroll
        for (int ks = 0; ks < 2; ++ks) {
            short8 afr[4], bfr[2];
            const int g = ks * 4 + (lane >> 4);
            #pragma unroll
            for (int fm = 0; fm < 4; ++fm) {
                int r = fm * 16 + (lane & 15);             // row within 64-row half
                afr[fm] = *(const short8*)&As[buf][wr * 4096 + r * 64 + ((g ^ (r & 7)) << 3)];
            }
            #pragma unroll
            for (int fn = 0; fn < 2; ++fn) {
                int n = wc * 32 + fn * 16 + (lane & 15);
                bfr[fn] = *(const short8*)&Bs[buf][n * 64 + ((g ^ (n & 7)) << 3)];
            }
            #pragma unroll
            for (int fm = 0; fm < 4; ++fm)
                #pragma unroll
                for (int fn = 0; fn < 2; ++fn)
                    acc[fm][fn] = __builtin_amdgcn_mfma_f32_16x16x32_bf16(
                        afr[fm], bfr[fn], acc[fm][fn], 0, 0, 0);
        }
    };

    // ---- prologue: 3 tiles in flight (18 staging loads after 34 key/bv)
    stage(0, 0);
    stage(1, 1);
    stage(2, 2);

    // ---- main loop: per kt wait stage(kt) landed (12 = stages kt+1,kt+2 in
    //      flight), barrier, issue stage(kt+3) (its buffer last read by
    //      compute(kt-1), finished at this barrier), compute(kt).
    #pragma unroll
    for (int kt = 0; kt < 16; ++kt) {
        if (kt <= 13)      asm volatile("s_waitcnt vmcnt(12)" ::: "memory");
        else if (kt == 14) asm volatile("s_waitcnt vmcnt(6)" ::: "memory");
        else               asm volatile("s_waitcnt vmcnt(0)" ::: "memory");
        __builtin_amdgcn_s_barrier();
        if (kt + 3 < 16) stage((kt + 3) & 3, kt + 3);
        compute(kt & 3);
    }

    // ---- epilogue: out = acc + bv + key (scattered 64B segments; E2 proved cheap)
    #pragma unroll
    for (int fm = 0; fm < 4; ++fm)
        #pragma unroll
        for (int fn = 0; fn < 2; ++fn) {
            int col = colA + fn * 16;
            #pragma unroll
            for (int i = 0; i < 4; ++i) {
                int r = rbaseA + fm * 16 + i;
                out[(size_t)r * N_DIM + col] = acc[fm][fn][i] + bvr[fn] + keyr[fm][fn][i];
            }
        }
}

extern "C" void kernel_launch(void* const* d_in, const int* in_sizes, int n_in,
                              void* d_out, int out_size, void* d_ws, size_t ws_size,
                              hipStream_t stream) {
    // setup_inputs order: 0 query, 1 key, 2 value, 3 Wq, 4 bq, 5 Wk, 6 bk, 7 Wv, 8 bv, 9 U
    const float* key   = (const float*)d_in[1];
    const float* value = (const float*)d_in[2];
    const float* Wv    = (const float*)d_in[7];
    const float* bv    = (const float*)d_in[8];
    float* out = (float*)d_out;

    short* Vb   = (short*)d_ws;                         // 2048*1024 bf16 = 4 MB
    short* WvTb = (short*)d_ws + (size_t)M_DIM * K_DIM; // 1024*1024 bf16 = 2 MB

    convert_kernel<<<1024 + 256, 256, 0, stream>>>(value, Wv, Vb, WvTb);
    gemm_kernel<<<256, 256, 0, stream>>>(Vb, WvTb, key, bv, out);
}

// Round 10
// 22.329 us; speedup vs baseline: 143.4844x; 1.1882x over previous
//
#include <hip/hip_runtime.h>
#include <hip/hip_bf16.h>

// out = value @ Wv + bv + key   (softmax over [.,.,1,1] is identically 1 -> ctx == v)
// M=2048 (batch), N=1024 (d_model out), K=1024 (d_model in)
//
// R8 finding: all 64x64 variants L2-read-BW-bound (~17-19 TB/s effective).
// R9 finding: 128x64 @256thr = 1 wave/SIMD + key-gather-poisoned vmcnt -> regressed.
// R10: 128x64 tile, 512 threads (8 waves, 2/SIMD), 4-buffer counted-vmcnt
//      (6/3/0, staging is the ONLY pre-epilogue VMEM), LDS-transpose epilogue
//      with fully-coalesced f32x4 key/bv/out.
//
// Tile layout (Vb, WvTb): tile (t, kt) = 4096 shorts at (t*16+kt)*4096;
// element (r, kk) at r*64 + ((c ^ (r&7))<<3) + (kk&7), c = kk>>3.

#define M_DIM 2048
#define N_DIM 1024
#define K_DIM 1024

typedef __attribute__((ext_vector_type(8))) short short8;
typedef __attribute__((ext_vector_type(4))) float f32x4;

__device__ inline unsigned rne_bf16(float f) {
    unsigned u = __builtin_bit_cast(unsigned, f);
    return (u + 0x7FFFu + ((u >> 16) & 1u)) >> 16;
}
__device__ inline unsigned pack2(float lo, float hi) {
    return rne_bf16(lo) | (rne_bf16(hi) << 16);
}
__device__ inline void gl_lds16(const short* g, short* l) {
    __builtin_amdgcn_global_load_lds((const __attribute__((address_space(1))) void*)g,
                                     (__attribute__((address_space(3))) void*)l,
                                     16, 0, 0);
}

// ---------------- K1: convert + transpose (unchanged, proven) ----------------
__global__ __launch_bounds__(256)
void convert_kernel(const float* __restrict__ value, const float* __restrict__ Wv,
                    short* __restrict__ Vb, short* __restrict__ WvTb) {
    __shared__ unsigned tr[64 * 36];
    const int b = blockIdx.x, tid = threadIdx.x;
    if (b < 1024) {
        int g = b * 256 + tid;
        int row = g >> 7, ch = g & 127;
        int kt = ch >> 3, c = ch & 7;
        int tm = row >> 6, r = row & 63;
        const float* p = value + (size_t)row * K_DIM + ch * 8;
        f32x4 a0 = *(const f32x4*)p;
        f32x4 a1 = *(const f32x4*)(p + 4);
        union { short8 s; unsigned u[4]; } o;
        o.u[0] = pack2(a0[0], a0[1]);
        o.u[1] = pack2(a0[2], a0[3]);
        o.u[2] = pack2(a1[0], a1[1]);
        o.u[3] = pack2(a1[2], a1[3]);
        *(short8*)&Vb[(size_t)(tm * 16 + kt) * 4096 + r * 64 + ((c ^ (r & 7)) << 3)] = o.s;
    } else {
        int b2 = b - 1024;
        int tn = b2 & 15, kt = b2 >> 4;
        #pragma unroll
        for (int s = 0; s < 2; ++s) {
            int kp = (tid >> 4) + s * 16;
            int n4 = (tid & 15) * 4;
            const float* bp = Wv + (size_t)(kt * 64 + 2 * kp) * N_DIM + tn * 64 + n4;
            f32x4 b0 = *(const f32x4*)bp;
            f32x4 b1 = *(const f32x4*)(bp + N_DIM);
            #pragma unroll
            for (int m = 0; m < 4; ++m)
                tr[(n4 + m) * 36 + kp] = pack2(b0[m], b1[m]);
        }
        __syncthreads();
        int n = tid >> 2;
        #pragma unroll
        for (int h = 0; h < 2; ++h) {
            int c = (tid & 3) + 4 * h;
            union { short8 s; unsigned u[4]; } o;
            #pragma unroll
            for (int p = 0; p < 4; ++p)
                o.u[p] = tr[n * 36 + c * 4 + p];
            *(short8*)&WvTb[(size_t)(tn * 16 + kt) * 4096 + n * 64 + ((c ^ (n & 7)) << 3)] = o.s;
        }
    }
}

// ------- K2: 128x64 tile, 512 threads, 4-buffer lookahead-3, LDS epilogue -------
__global__ __launch_bounds__(512)
void gemm_kernel(const short* __restrict__ Vb, const short* __restrict__ WvTb,
                 const float* __restrict__ key, const float* __restrict__ bv,
                 float* __restrict__ out) {
    __shared__ __align__(16) short As[4][8192];   // 64 KB (128 rows x 64 k per buf)
    __shared__ __align__(16) short Bs[4][4096];   // 32 KB

    const int tid = threadIdx.x;
    const int bid = blockIdx.x;
    // XCD swizzle: xcd = bid&7 owns 32 blocks = 2 bm2-bands x 16 bn.
    const int xcd = bid & 7, idx = bid >> 3;
    const int bm2 = xcd * 2 + (idx >> 4);   // 0..15  (128-row band)
    const int bn  = idx & 15;               // 0..15  (64-col band)
    const int lane = tid & 63;
    const int wid = tid >> 6;               // 0..7
    const int wr = wid >> 1;                // 0..3: rows wr*32..+31
    const int wc = wid & 1;                 // 0..1: cols wc*32..+31

    const short* Ab0 = Vb + (size_t)(bm2 * 2) * 16 * 4096;       // rows +0..63
    const short* Ab1 = Vb + (size_t)(bm2 * 2 + 1) * 16 * 4096;   // rows +64..127
    const short* Bb  = WvTb + (size_t)bn * 16 * 4096;
    const int row0 = bm2 * 128, col0 = bn * 64;

    f32x4 acc[2][2] = {};

    auto stage = [&](int buf, int kt) {      // 3 x gl_lds16 per thread
        gl_lds16(Ab0 + (size_t)kt * 4096 + tid * 8, &As[buf][tid * 8]);
        gl_lds16(Ab1 + (size_t)kt * 4096 + tid * 8, &As[buf][4096 + tid * 8]);
        gl_lds16(Bb  + (size_t)kt * 4096 + tid * 8, &Bs[buf][tid * 8]);
    };

    auto compute = [&](int buf) {
        #pragma unroll
        for (int ks = 0; ks < 2; ++ks) {
            short8 afr[2], bfr[2];
            const int g = ks * 4 + (lane >> 4);
            #pragma unroll
            for (int fm = 0; fm < 2; ++fm) {
                int r = wr * 32 + fm * 16 + (lane & 15);   // 0..127
                afr[fm] = *(const short8*)&As[buf][r * 64 + ((g ^ (r & 7)) << 3)];
            }
            #pragma unroll
            for (int fn = 0; fn < 2; ++fn) {
                int n = wc * 32 + fn * 16 + (lane & 15);
                bfr[fn] = *(const short8*)&Bs[buf][n * 64 + ((g ^ (n & 7)) << 3)];
            }
            #pragma unroll
            for (int fm = 0; fm < 2; ++fm)
                #pragma unroll
                for (int fn = 0; fn < 2; ++fn)
                    acc[fm][fn] = __builtin_amdgcn_mfma_f32_16x16x32_bf16(
                        afr[fm], bfr[fn], acc[fm][fn], 0, 0, 0);
        }
    };

    // ---- prologue: 3 tiles in flight (9 loads/thread outstanding; staging is
    //      the ONLY VMEM before the epilogue -> counted waits track it exactly)
    stage(0, 0);
    stage(1, 1);
    stage(2, 2);

    #pragma unroll
    for (int kt = 0; kt < 16; ++kt) {
        if (kt <= 13)      asm volatile("s_waitcnt vmcnt(6)" ::: "memory");
        else if (kt == 14) asm volatile("s_waitcnt vmcnt(3)" ::: "memory");
        else               asm volatile("s_waitcnt vmcnt(0)" ::: "memory");
        __builtin_amdgcn_s_barrier();
        if (kt + 3 < 16) stage((kt + 3) & 3, kt + 3);
        compute(kt & 3);
    }

    // ---- epilogue: acc -> LDS transpose -> coalesced f32x4 key/bv/out
    __syncthreads();                       // everyone done reading As/Bs
    float* T = (float*)&As[0][0];          // 128 x 68 f32 = 34.8 KB (fits in As)
    #pragma unroll
    for (int fm = 0; fm < 2; ++fm)
        #pragma unroll
        for (int fn = 0; fn < 2; ++fn) {
            int c = wc * 32 + fn * 16 + (lane & 15);
            #pragma unroll
            for (int i = 0; i < 4; ++i) {
                int r = wr * 32 + fm * 16 + (lane >> 4) * 4 + i;
                T[r * 68 + c] = acc[fm][fn][i];
            }
        }
    __syncthreads();
    #pragma unroll
    for (int it = 0; it < 4; ++it) {
        int r = it * 32 + (tid >> 4);      // 32 rows per iteration
        int q = tid & 15;                  // 16 quads cover 64 cols
        f32x4 vv = *(f32x4*)&T[r * 68 + q * 4];
        int grow = row0 + r, gcol = col0 + q * 4;
        f32x4 kv = *(const f32x4*)&key[(size_t)grow * N_DIM + gcol];
        f32x4 bb = *(const f32x4*)&bv[gcol];
        vv = vv + kv + bb;
        *(f32x4*)&out[(size_t)grow * N_DIM + gcol] = vv;
    }
}

extern "C" void kernel_launch(void* const* d_in, const int* in_sizes, int n_in,
                              void* d_out, int out_size, void* d_ws, size_t ws_size,
                              hipStream_t stream) {
    // setup_inputs order: 0 query, 1 key, 2 value, 3 Wq, 4 bq, 5 Wk, 6 bk, 7 Wv, 8 bv, 9 U
    const float* key   = (const float*)d_in[1];
    const float* value = (const float*)d_in[2];
    const float* Wv    = (const float*)d_in[7];
    const float* bv    = (const float*)d_in[8];
    float* out = (float*)d_out;

    short* Vb   = (short*)d_ws;                         // 2048*1024 bf16 = 4 MB
    short* WvTb = (short*)d_ws + (size_t)M_DIM * K_DIM; // 1024*1024 bf16 = 2 MB

    convert_kernel<<<1024 + 256, 256, 0, stream>>>(value, Wv, Vb, WvTb);
    gemm_kernel<<<256, 512, 0, stream>>>(Vb, WvTb, key, bv, out);
}